// Round 8
// baseline (75.911 us; speedup 1.0000x reference)
//
#include <hip/hip_runtime.h>

#define N_NODES 10000
#define FEATS 32
#define HEADS 4
#define SAMPLES 256
#define N_BATCH 2048
#define NGROUP 40                       // ceil(N_NODES / 256)
#define NWORDS (NGROUP * 4)             // 160 u64 words per mask row

typedef float f32x4 __attribute__((ext_vector_type(4)));

// ---------------- Fused kernel: one block per edge -------------------------
// Phase A: block builds its edge's two sign bitmasks (rows dst, src of the
//   +-1 symmetric edge_mat) in LDS. 80 KB sequential HBM per block via
//   NONTEMPORAL float4 loads (keeps the 164 MB stream from evicting pos/L2).
// Phase B: wave h computes head h with the register-direct 4-lane-per-row
//   gather (R6 structure): lane l loads chunks (l&3),(l&3)+4 of row group
//   g=l>>2 (each load instr = 16 rows x contiguous 64 B), 2-level shfl_xor
//   butterfly gives full dot/nrm on all 4 lanes; em/exp/acc redundant per
//   lane (4x counted, folded via den+32). Partials combine in LDS; plain
//   store of out[n] (no atomics, no workspace, single launch).
// Across blocks, phase-A (HBM pipe) overlaps phase-B (L2/VALU pipes),
// removing the k1->k2 serialization of the split design.
__global__ __launch_bounds__(256) void madgraph_fused(
    const int* __restrict__ edge,        // (N_BATCH, 2)
    const int* __restrict__ mid0,        // (H, N_BATCH, S)
    const int* __restrict__ mid1,        // (H, N_BATCH, S)
    const float* __restrict__ pos,       // (H, N_NODES, F)
    const float* __restrict__ field,     // (H, N_NODES, F)
    const float* __restrict__ unc,       // scalar
    const float* __restrict__ edge_mat,  // (N_NODES, N_NODES), +-1, symmetric
    float* __restrict__ out)             // (N_BATCH)
{
    const int n    = blockIdx.x;
    const int tid  = threadIdx.x;
    const int w    = tid >> 6;   // wave = head
    const int lane = tid & 63;

    __shared__ unsigned long long s_mask[2 * NWORDS]; // 2.5 KB, shared by waves
    __shared__ float s_num[HEADS], s_den[HEADS];

    const int src = edge[2 * n];
    const int dst = edge[2 * n + 1];
    const float U = unc[0];

    // ---- Phase A: sign bitmasks for rows dst (r=0, side0 via symmetry)
    //      and src (r=1, side1). Nontemporal streaming loads.
    #pragma unroll
    for (int r = 0; r < 2; ++r) {
        const float* rp = edge_mat + (size_t)(r ? src : dst) * N_NODES;
        for (int g = w; g < NGROUP; g += HEADS) {
            int base = g * 256 + lane * 4;
            f32x4 v = {-1.f, -1.f, -1.f, -1.f};
            if (base < N_NODES)
                v = __builtin_nontemporal_load((const f32x4*)(rp + base));
            unsigned long long b0 = __ballot(v.x > 0.f);
            unsigned long long b1 = __ballot(v.y > 0.f);
            unsigned long long b2 = __ballot(v.z > 0.f);
            unsigned long long b3 = __ballot(v.w > 0.f);
            if (lane < 4) {
                unsigned long long bb = lane == 0 ? b0 : lane == 1 ? b1
                                      : lane == 2 ? b2 : b3;
                s_mask[r * NWORDS + g * 4 + lane] = bb;
            }
        }
    }
    __syncthreads();

    // ---- Phase B: head w, register-direct gathers (cached loads).
    const int h = w;
    const float* posh   = pos   + (size_t)h * N_NODES * FEATS;
    const float* fieldh = field + (size_t)h * N_NODES * FEATS;

    const int q = lane & 3;    // lane's chunk pair: q and q+4
    const int g = lane >> 2;   // row-group index within 16

    // Anchor/field chunks for both sides (8 float4 = 32 VGPRs).
    float4 A[2][2], F[2][2];
    #pragma unroll
    for (int sd = 0; sd < 2; ++sd) {
        const float4* pa = (const float4*)(posh   + (size_t)(sd ? dst : src) * FEATS);
        const float4* pf = (const float4*)(fieldh + (size_t)(sd ? src : dst) * FEATS);
        A[sd][0] = pa[q];
        A[sd][1] = pa[q + 4];
        F[sd][0] = pf[q];
        F[sd][1] = pf[q + 4];
    }

    // All mids in registers (statically indexed under full unroll).
    const size_t sb = ((size_t)h * N_BATCH + n) * SAMPLES;
    int mm[8];
    #pragma unroll
    for (int c = 0; c < 8; ++c)
        mm[c] = (c < 4 ? mid0 : mid1)[sb + (c & 3) * 64 + lane];

    float num = 0.f, den = 0.f;

    #pragma unroll
    for (int c = 0; c < 8; ++c) {
        const int side = c >> 2;
        #pragma unroll
        for (int t = 0; t < 4; ++t) {
            const int m = __shfl(mm[c], t * 16 + g);
            const float4* rp = (const float4*)(posh + (size_t)m * FEATS);
            float4 b0 = rp[q];
            float4 b1 = rp[q + 4];

            float dh = 0.f, nh = 0.f;
            {
                float4 a = A[side][0], f = F[side][0];
                float dx = a.x - b0.x, dy = a.y - b0.y,
                      dz = a.z - b0.z, dw = a.w - b0.w;
                dh += dx * f.x + dy * f.y + dz * f.z + dw * f.w;
                nh += dx * dx + dy * dy + dz * dz + dw * dw;
            }
            {
                float4 a = A[side][1], f = F[side][1];
                float dx = a.x - b1.x, dy = a.y - b1.y,
                      dz = a.z - b1.z, dw = a.w - b1.w;
                dh += dx * f.x + dy * f.y + dz * f.z + dw * f.w;
                nh += dx * dx + dy * dy + dz * dz + dw * dw;
            }
            dh += __shfl_xor(dh, 1); nh += __shfl_xor(nh, 1);
            dh += __shfl_xor(dh, 2); nh += __shfl_xor(nh, 2);

            const unsigned long long wbits =
                s_mask[side * NWORDS + ((m >> 8) << 2) + (m & 3)];
            const float em = ((wbits >> ((m >> 2) & 63)) & 1ull) ? U : -U;

            const float wgt = __expf(1.0f - sqrtf(nh));
            num += (dh + em) * wgt;   // each sample counted by 4 lanes
            den += wgt;
        }
    }

    // Wave-wide butterfly reduction (64 lanes).
    #pragma unroll
    for (int off = 32; off > 0; off >>= 1) {
        num += __shfl_xor(num, off);
        den += __shfl_xor(den, off);
    }
    if (lane == 0) { s_num[w] = num; s_den[w] = den; }
    __syncthreads();

    if (tid == 0) {
        // Per head: num,den are 4x true sums; sentinels add 8 true -> +32.
        float acc = 0.f;
        #pragma unroll
        for (int hh = 0; hh < HEADS; ++hh)
            acc += s_num[hh] / (s_den[hh] + 32.0f);
        out[n] = 0.25f * acc;
    }
}

extern "C" void kernel_launch(void* const* d_in, const int* in_sizes, int n_in,
                              void* d_out, int out_size, void* d_ws, size_t ws_size,
                              hipStream_t stream) {
    const int*   edge     = (const int*)  d_in[0];
    const int*   mid0     = (const int*)  d_in[1];
    const int*   mid1     = (const int*)  d_in[2];
    const float* pos      = (const float*)d_in[3];
    const float* field    = (const float*)d_in[4];
    const float* unc      = (const float*)d_in[5];
    const float* edge_mat = (const float*)d_in[6];
    float*       out      = (float*)d_out;

    madgraph_fused<<<N_BATCH, 256, 0, stream>>>(edge, mid0, mid1, pos, field,
                                                unc, edge_mat, out);
}

// Round 9
// 61.320 us; speedup vs baseline: 1.2380x; 1.2380x over previous
//
#include <hip/hip_runtime.h>

#define N_NODES 10000
#define FEATS 32
#define HEADS 4
#define SAMPLES 256
#define N_BATCH 2048
#define NGROUP 40                       // ceil(N_NODES / 256)
#define NWORDS (NGROUP * 4)             // 160 u64 words per mask row

// ---------------- Kernel 1: edge_mat rows -> sign bitmasks in d_ws ----------
// Block n: row dst (r=0, side0 via symmetry) and row src (r=1, side1).
// Pure streaming HBM (80 KB/block sequential); writes 2.5 KB bitmask; zeroes
// out[n] so k2 can atomically accumulate (replays stay idempotent).
__global__ __launch_bounds__(256) void mask_kernel(
    const int* __restrict__ edge,
    const float* __restrict__ edge_mat,
    unsigned long long* __restrict__ ws_mask,
    float* __restrict__ out)
{
    const int n    = blockIdx.x;
    const int tid  = threadIdx.x;
    const int wave = tid >> 6;
    const int lane = tid & 63;

    const int src = edge[2 * n];
    const int dst = edge[2 * n + 1];
    if (tid == 0) out[n] = 0.f;

    unsigned long long* wsn = ws_mask + (size_t)n * 2 * NWORDS;

    #pragma unroll
    for (int r = 0; r < 2; ++r) {
        const float* rp = edge_mat + (size_t)(r ? src : dst) * N_NODES;
        for (int g = wave; g < NGROUP; g += 4) {
            int base = g * 256 + lane * 4;
            float4 v = make_float4(-1.f, -1.f, -1.f, -1.f);
            if (base < N_NODES) v = *(const float4*)(rp + base);
            unsigned long long b0 = __ballot(v.x > 0.f);
            unsigned long long b1 = __ballot(v.y > 0.f);
            unsigned long long b2 = __ballot(v.z > 0.f);
            unsigned long long b3 = __ballot(v.w > 0.f);
            if (lane < 4) {
                unsigned long long b = lane == 0 ? b0 : lane == 1 ? b1
                                     : lane == 2 ? b2 : b3;
                wsn[r * NWORDS + g * 4 + lane] = b;
            }
        }
    }
}

// ---------------- Kernel 2: register-direct gather, 4 lanes per row ---------
// Block b in [0,2048): head h = b & 3; wave w handles edge n = (b>>2) + 512w.
// Round-robin XCD (b % 8) => XCD x only ever touches pos[x & 3] (1.28 MB,
// L2-resident). Lane l loads chunks (l&3),(l&3)+4 of row group g = l>>2
// (each load instr = 16 rows x contiguous 64 B = optimal coalescing).
//
// R8 change (single variable vs R6): per chunk, ALL 8 gathers (4 rows x 2
// halves) are issued into registers BEFORE any consumption -> 8 outstanding
// loads per wave (4x deeper MLP), then 4 compute iterations run on the
// batched registers. __launch_bounds__(256,4) pins VGPR<=128 so occupancy
// stays 16 waves/CU despite the wider live range.
__global__ __launch_bounds__(256, 4) void madgraph_kernel(
    const int* __restrict__ edge,
    const int* __restrict__ mid0,
    const int* __restrict__ mid1,
    const float* __restrict__ pos,
    const float* __restrict__ field,
    const float* __restrict__ unc,
    const unsigned long long* __restrict__ ws_mask,
    float* __restrict__ out)
{
    const int b    = blockIdx.x;
    const int h    = b & 3;
    const int tid  = threadIdx.x;
    const int w    = tid >> 6;            // wave -> edge slot
    const int lane = tid & 63;
    const int n    = (b >> 2) + 512 * w;  // this wave's edge

    __shared__ unsigned long long s_mask[4][2 * NWORDS]; // 4 x 2.5 KB

    const int src = edge[2 * n];
    const int dst = edge[2 * n + 1];
    const float U = unc[0];

    // Stage this wave's edge bitmasks (320 u64 = 5 per lane, coalesced).
    const unsigned long long* wsn = ws_mask + (size_t)n * 2 * NWORDS;
    #pragma unroll
    for (int k = 0; k < 5; ++k)
        s_mask[w][k * 64 + lane] = wsn[k * 64 + lane];

    const float* posh   = pos   + (size_t)h * N_NODES * FEATS;
    const float* fieldh = field + (size_t)h * N_NODES * FEATS;

    const int q = lane & 3;    // lane's chunk pair: q and q+4
    const int g = lane >> 2;   // row-group index within 16

    // Anchor/field chunks for both sides (8 float4 = 32 VGPRs).
    float4 A[2][2], F[2][2];
    #pragma unroll
    for (int sd = 0; sd < 2; ++sd) {
        const float4* pa = (const float4*)(posh   + (size_t)(sd ? dst : src) * FEATS);
        const float4* pf = (const float4*)(fieldh + (size_t)(sd ? src : dst) * FEATS);
        A[sd][0] = pa[q];
        A[sd][1] = pa[q + 4];
        F[sd][0] = pf[q];
        F[sd][1] = pf[q + 4];
    }

    // All mids in registers (statically indexed under full unroll).
    const size_t sb = ((size_t)h * N_BATCH + n) * SAMPLES;
    int mm[8];
    #pragma unroll
    for (int c = 0; c < 8; ++c)
        mm[c] = (c < 4 ? mid0 : mid1)[sb + (c & 3) * 64 + lane];

    float num = 0.f, den = 0.f;

    #pragma unroll
    for (int c = 0; c < 8; ++c) {
        const int side = c >> 2;

        // --- Batch phase: issue all 8 independent gathers for this chunk.
        int    mArr[4];
        float4 B0[4], B1[4];
        #pragma unroll
        for (int t = 0; t < 4; ++t)
            mArr[t] = __shfl(mm[c], t * 16 + g);
        #pragma unroll
        for (int t = 0; t < 4; ++t) {
            const float4* rp = (const float4*)(posh + (size_t)mArr[t] * FEATS);
            B0[t] = rp[q];
            B1[t] = rp[q + 4];
        }

        // --- Compute phase: consume the batched registers.
        #pragma unroll
        for (int t = 0; t < 4; ++t) {
            float dh = 0.f, nh = 0.f;
            {
                float4 a = A[side][0], f = F[side][0];
                float dx = a.x - B0[t].x, dy = a.y - B0[t].y,
                      dz = a.z - B0[t].z, dw = a.w - B0[t].w;
                dh += dx * f.x + dy * f.y + dz * f.z + dw * f.w;
                nh += dx * dx + dy * dy + dz * dz + dw * dw;
            }
            {
                float4 a = A[side][1], f = F[side][1];
                float dx = a.x - B1[t].x, dy = a.y - B1[t].y,
                      dz = a.z - B1[t].z, dw = a.w - B1[t].w;
                dh += dx * f.x + dy * f.y + dz * f.z + dw * f.w;
                nh += dx * dx + dy * dy + dz * dz + dw * dw;
            }
            dh += __shfl_xor(dh, 1); nh += __shfl_xor(nh, 1);
            dh += __shfl_xor(dh, 2); nh += __shfl_xor(nh, 2);

            const unsigned long long wbits =
                s_mask[w][side * NWORDS + ((mArr[t] >> 8) << 2) + (mArr[t] & 3)];
            const float em = ((wbits >> ((mArr[t] >> 2) & 63)) & 1ull) ? U : -U;

            const float wgt = __expf(1.0f - sqrtf(nh));
            num += (dh + em) * wgt;   // each sample counted by 4 lanes
            den += wgt;
        }
    }

    // Wave-wide butterfly reduction (64 lanes).
    #pragma unroll
    for (int off = 32; off > 0; off >>= 1) {
        num += __shfl_xor(num, off);
        den += __shfl_xor(den, off);
    }
    if (lane == 0) {
        // num,den are 4x true sums; sentinels add 8 true -> +32 scaled.
        // 0.25*(4N)/(4D+32) == 0.25*N/(D+8). k1 zeroed out[n] this launch.
        atomicAdd(out + n, 0.25f * (num / (den + 32.0f)));
    }
}

extern "C" void kernel_launch(void* const* d_in, const int* in_sizes, int n_in,
                              void* d_out, int out_size, void* d_ws, size_t ws_size,
                              hipStream_t stream) {
    const int*   edge     = (const int*)  d_in[0];
    const int*   mid0     = (const int*)  d_in[1];
    const int*   mid1     = (const int*)  d_in[2];
    const float* pos      = (const float*)d_in[3];
    const float* field    = (const float*)d_in[4];
    const float* unc      = (const float*)d_in[5];
    const float* edge_mat = (const float*)d_in[6];
    float*       out      = (float*)d_out;
    unsigned long long* ws_mask = (unsigned long long*)d_ws; // 5.24 MB used

    mask_kernel<<<N_BATCH, 256, 0, stream>>>(edge, edge_mat, ws_mask, out);
    madgraph_kernel<<<N_BATCH, 256, 0, stream>>>(edge, mid0, mid1, pos,
                                                 field, unc, ws_mask, out);
}